// Round 13
// baseline (109.586 us; speedup 1.0000x reference)
//
#include <hip/hip_runtime.h>
#include <hip/hip_bf16.h>

#define HM_W 512
#define HM_H 512
#define PW   508   // 512 - 5 + 1
#define NBATCH 128

__device__ __forceinline__ void load_row8(const float* __restrict__ hm, int y, int c0, float v[8]) {
    const float4* rp = reinterpret_cast<const float4*>(hm + y * HM_W + c0);
    float4 a = rp[0];
    float4 b = rp[1];
    v[0]=a.x; v[1]=a.y; v[2]=a.z; v[3]=a.w;
    v[4]=b.x; v[5]=b.y; v[6]=b.z; v[7]=b.w;
}

// Per-lane 5-wide window sums from per-lane colsums s[0..7] (cols lane*8..lane*8+7),
// cross-lane tail via shfl, then wave-wide argmax (tie-break: lowest column).
// Whole wave must be active. All lanes end with the result.
__device__ __forceinline__ void row_best_shfl(const float s[8], int lane, float& bv, int& bc) {
    float cb[12];
#pragma unroll
    for (int j = 0; j < 8; ++j) cb[j] = s[j];
#pragma unroll
    for (int j = 0; j < 4; ++j) cb[8 + j] = __shfl_down(s[j], 1);
    bv = -__builtin_inff();
    bc = 0x7fffffff;
    int c0 = lane * 8;
#pragma unroll
    for (int j = 0; j < 8; ++j) {
        int c = c0 + j;
        float w = cb[j] + cb[j + 1] + cb[j + 2] + cb[j + 3] + cb[j + 4];
        if (c < PW && w > bv) { bv = w; bc = c; }   // ascending c keeps lowest col on tie
    }
#pragma unroll
    for (int m = 1; m < 64; m <<= 1) {
        float ov = __shfl_xor(bv, m);
        int   oc = __shfl_xor(bc, m);
        if (ov > bv || (ov == bv && oc < bc)) { bv = ov; bc = oc; }
    }
}

// Fused kernel, "last block does the epilogue" (NO spinning — r9's failure mode
// was 128 blocks POLLING agent-scope acquires, invalidating L2 continuously).
// Blocks: 8 per batch (blk>>3 = batch). Phase-1 role = r2-exact rolling-window
// row scan. After a barrier (vmcnt(0) drain) each block does ONE acq_rel
// atomicAdd on cnt[b]; the 8th arriver (old==7) acquires (sees all 8 blocks'
// ws stores: their releases ordered the stores to the coherent point) and runs
// the r12 role-split phase-2 for batch b: waves 0..2 repair 3 zone rows each,
// wave 3 scans "best outside zone", one barrier per interval, 10-candidate
// combine. Work assignment varies run-to-run; output is deterministic.
__global__ void __launch_bounds__(256) fused_kernel(const float* __restrict__ hm_all,
                              float* __restrict__ rowv_ws, int* __restrict__ rowc_ws,
                              int* __restrict__ cnt, int* __restrict__ out) {
    int t = threadIdx.x;
    int wave = t >> 6, lane = t & 63;
    int c0 = lane * 8;
    int blk = blockIdx.x;
    int b = blk >> 3;
    const float* hm = hm_all + (size_t)b * HM_W * HM_H;

    __shared__ float rowv[512];
    __shared__ int   rowc[512];
    __shared__ float updv[2][9];
    __shared__ int   updc[2][9];
    __shared__ float obv[2];
    __shared__ int   obr[2], obc[2];
    __shared__ int   lastFlag;

    // ---------------- phase-1 role (round-2 exact math) ----------------
    {
        int rbase = ((blk & 7) * 4 + wave) * 16;   // max 496 < PW: all waves work
        float w0[8], w1[8], w2[8], w3[8], w4[8];
        load_row8(hm, rbase + 0, c0, w0);
        load_row8(hm, rbase + 1, c0, w1);
        load_row8(hm, rbase + 2, c0, w2);
        load_row8(hm, rbase + 3, c0, w3);

#pragma unroll
        for (int rr = 0; rr < 16; ++rr) {
            int y = rbase + rr;
            if (y >= PW) break;                 // wave-uniform
            load_row8(hm, y + 4, c0, w4);
            float s[8];
#pragma unroll
            for (int j = 0; j < 8; ++j)
                s[j] = ((((w0[j] + w1[j]) + w2[j]) + w3[j]) + w4[j]);
            float bv; int bc;
            row_best_shfl(s, lane, bv, bc);
            if (lane == 0) {
                rowv_ws[b * 512 + y] = bv;
                rowc_ws[b * 512 + y] = bc;
            }
#pragma unroll
            for (int j = 0; j < 8; ++j) { w0[j] = w1[j]; w1[j] = w2[j]; w2[j] = w3[j]; w3[j] = w4[j]; }
        }
    }

    __syncthreads();   // block's ws stores drained (compiler emits vmcnt(0) at barrier)
    if (t == 0) {
        int old = __hip_atomic_fetch_add(&cnt[b], 1, __ATOMIC_ACQ_REL,
                                         __HIP_MEMORY_SCOPE_AGENT);
        lastFlag = (old == 7);
    }
    __syncthreads();
    if (!lastFlag) return;

    // ---------------- epilogue: phase-2 (r12 role-split, 4 waves) ----------------
    for (int i = t; i < 512; i += 256) {
        if (i < PW) { rowv[i] = rowv_ws[b * 512 + i]; rowc[i] = rowc_ws[b * 512 + i]; }
        else        { rowv[i] = -__builtin_inff();    rowc[i] = 0; }
    }
    __syncthreads();

    int zrr[6], zcc[6];
    int pz0 = 0, pzn = 0;                  // previous zone range (uniform)
    int fr, fc;

    // ---- interval 0 bootstrap: full scan (LDS only), all waves redundant ----
    {
        float bv = -__builtin_inff(); int bi = 0x7fffffff;
#pragma unroll
        for (int j = 0; j < 8; ++j) {
            int idx = j * 64 + lane;
            float v = rowv[idx];
            if (v > bv) { bv = v; bi = idx; }   // ascending idx: lowest row on tie
        }
#pragma unroll
        for (int m = 1; m < 64; m <<= 1) {
            float ov = __shfl_xor(bv, m);
            int   oi = __shfl_xor(bi, m);
            if (ov > bv || (ov == bv && oi < bi)) { bv = ov; bi = oi; }
        }
        fr = bi; fc = rowc[fr];
    }
    zrr[0] = fr; zcc[0] = fc;
    if (t == 0) {
        out[b * 12 + 0] = fc + 2;   // SWAP_RC: (c+R, r+R)
        out[b * 12 + 1] = fr + 2;
    }

#pragma unroll
    for (int it = 0; it < 5; ++it) {
        int wbuf = it & 1;                 // this interval's repair buffer
        int rbuf = wbuf ^ 1;               // previous interval's repairs

        int zlo = fr - 4 < 0 ? 0 : fr - 4;
        int zhi = fr + 4 > PW - 1 ? PW - 1 : fr + 4;
        int zn  = zhi - zlo + 1;

        // ---- patch rowv/rowc with the previous zone's repairs (race-benign:
        //      the scanner reads those rows via the updv[rbuf] override) ----
        if (t < 9 && t < pzn) {
            rowv[pz0 + t] = updv[rbuf][t];
            rowc[pz0 + t] = updc[rbuf][t];
        }

        if (wave < 3) {
            // ---- repair: wave w recomputes zone rows zlo+3w+q, q=0..2 ----
#pragma unroll
            for (int q = 0; q < 3; ++q) {
                int li = wave * 3 + q;     // 0..8
                if (li < zn) {             // wave-uniform
                    int y = zlo + li;
                    float s[8];
#pragma unroll
                    for (int j = 0; j < 8; ++j) s[j] = 0.f;
#pragma unroll
                    for (int i = 0; i < 5; ++i) {
                        float v[8];
                        load_row8(hm, y + i, c0, v);
#pragma unroll
                        for (int k = 0; k < 6; ++k) {
                            if (k <= it) {     // compile-time under unroll
                                if ((unsigned)(y + i - zrr[k]) < 5u) {   // wave-uniform
#pragma unroll
                                    for (int j = 0; j < 8; ++j)
                                        if ((unsigned)(c0 + j - zcc[k]) < 5u) v[j] = 0.f;
                                }
                            }
                        }
#pragma unroll
                        for (int j = 0; j < 8; ++j) s[j] += v[j];
                    }
                    float nv; int nc;
                    row_best_shfl(s, lane, nv, nc);
                    if (lane == 0) { updv[wbuf][li] = nv; updc[wbuf][li] = nc; }
                }
            }
        } else if (wave == 3) {
            // ---- scanner: best over rows OUTSIDE the current zone, overriding
            //      the previous zone's rows from updv[rbuf] ----
            float bv = -__builtin_inff(); int bi = 0x7fffffff;
#pragma unroll
            for (int j = 0; j < 8; ++j) {
                int idx = j * 64 + lane;
                float v = rowv[idx];
                unsigned u = (unsigned)(idx - pz0);
                if (u < (unsigned)pzn) v = updv[rbuf][u];
                if ((unsigned)(idx - zlo) < (unsigned)zn) v = -__builtin_inff();
                if (v > bv) { bv = v; bi = idx; }
            }
#pragma unroll
            for (int m = 1; m < 64; m <<= 1) {
                float ov = __shfl_xor(bv, m);
                int   oi = __shfl_xor(bi, m);
                if (ov > bv || (ov == bv && oi < bi)) { bv = ov; bi = oi; }
            }
            if (lane == 0) {
                int bc2 = rowc[bi];
                unsigned u = (unsigned)(bi - pz0);
                if (u < (unsigned)pzn) bc2 = updc[rbuf][u];
                obv[wbuf] = bv; obr[wbuf] = bi; obc[wbuf] = bc2;
            }
        }

        __syncthreads();   // the ONLY barrier per interval

        // ---- combine: outside-best + the zn repaired zone rows (ascending) ----
        {
            float bv = obv[wbuf]; int br = obr[wbuf]; int bc2 = obc[wbuf];
#pragma unroll
            for (int u = 0; u < 9; ++u) {
                if (u < zn) {
                    int yy = zlo + u;
                    float v = updv[wbuf][u];
                    if (v > bv || (v == bv && yy < br)) { bv = v; br = yy; bc2 = updc[wbuf][u]; }
                }
            }
            fr = br; fc = bc2;
        }
        zrr[it + 1] = fr; zcc[it + 1] = fc;   // static index under unroll
        if (t == 0) {
            out[b * 12 + (it + 1) * 2 + 0] = fc + 2;
            out[b * 12 + (it + 1) * 2 + 1] = fr + 2;
        }

        pz0 = zlo; pzn = zn;
    }
}

extern "C" void kernel_launch(void* const* d_in, const int* in_sizes, int n_in,
                              void* d_out, int out_size, void* d_ws, size_t ws_size,
                              hipStream_t stream) {
    const float* hm = (const float*)d_in[0];
    int* out = (int*)d_out;
    float* rowv_ws = (float*)d_ws;
    int*   rowc_ws = (int*)((char*)d_ws + (size_t)128 * 512 * sizeof(float));
    int*   cnt     = (int*)((char*)d_ws + (size_t)2 * 128 * 512 * sizeof(float));

    hipMemsetAsync(cnt, 0, NBATCH * sizeof(int), stream);
    fused_kernel<<<dim3(1024), dim3(256), 0, stream>>>(hm, rowv_ws, rowc_ws, cnt, out);
}

// Round 14
// 50.824 us; speedup vs baseline: 2.1562x; 2.1562x over previous
//
#include <hip/hip_runtime.h>
#include <hip/hip_bf16.h>

#define HM_W 512
#define HM_H 512
#define PW   508   // 512 - 5 + 1

__device__ __forceinline__ void load_row8(const float* __restrict__ hm, int y, int c0, float v[8]) {
    const float4* rp = reinterpret_cast<const float4*>(hm + y * HM_W + c0);
    float4 a = rp[0];
    float4 b = rp[1];
    v[0]=a.x; v[1]=a.y; v[2]=a.z; v[3]=a.w;
    v[4]=b.x; v[5]=b.y; v[6]=b.z; v[7]=b.w;
}

// Per-lane 5-wide window sums from per-lane colsums s[0..7] (cols lane*8..lane*8+7),
// cross-lane tail via shfl, then wave-wide argmax (tie-break: lowest column).
// Whole wave must be active. All lanes end with the result.
__device__ __forceinline__ void row_best_shfl(const float s[8], int lane, float& bv, int& bc) {
    float cb[12];
#pragma unroll
    for (int j = 0; j < 8; ++j) cb[j] = s[j];
#pragma unroll
    for (int j = 0; j < 4; ++j) cb[8 + j] = __shfl_down(s[j], 1);
    bv = -__builtin_inff();
    bc = 0x7fffffff;
    int c0 = lane * 8;
#pragma unroll
    for (int j = 0; j < 8; ++j) {
        int c = c0 + j;
        float w = cb[j] + cb[j + 1] + cb[j + 2] + cb[j + 3] + cb[j + 4];
        if (c < PW && w > bv) { bv = w; bc = c; }   // ascending c keeps lowest col on tie
    }
#pragma unroll
    for (int m = 1; m < 64; m <<= 1) {
        float ov = __shfl_xor(bv, m);
        int   oc = __shfl_xor(bc, m);
        if (ov > bv || (ov == bv && oc < bc)) { bv = ov; bc = oc; }
    }
}

// Phase 1 (round-2 exact, best known): rolling 5-row register window,
// 16 aggregate rows per wave from 20 row-loads. grid = (8,128), block = 256.
__global__ void phase1_kernel(const float* __restrict__ hm_all,
                              float* __restrict__ rowv_ws, int* __restrict__ rowc_ws) {
    int b = blockIdx.y;
    int wave = threadIdx.x >> 6;
    int lane = threadIdx.x & 63;
    int c0 = lane * 8;
    const float* hm = hm_all + (size_t)b * HM_W * HM_H;

    int rbase = (blockIdx.x * 4 + wave) * 16;
    if (rbase >= PW) return;

    float w0[8], w1[8], w2[8], w3[8], w4[8];
    load_row8(hm, rbase + 0, c0, w0);
    load_row8(hm, rbase + 1, c0, w1);
    load_row8(hm, rbase + 2, c0, w2);
    load_row8(hm, rbase + 3, c0, w3);

#pragma unroll
    for (int rr = 0; rr < 16; ++rr) {
        int y = rbase + rr;
        if (y >= PW) break;                 // wave-uniform
        load_row8(hm, y + 4, c0, w4);
        float s[8];
#pragma unroll
        for (int j = 0; j < 8; ++j)
            s[j] = ((((w0[j] + w1[j]) + w2[j]) + w3[j]) + w4[j]);
        float bv; int bc;
        row_best_shfl(s, lane, bv, bc);
        if (lane == 0) {
            rowv_ws[b * 512 + y] = bv;
            rowc_ws[b * 512 + y] = bc;
        }
#pragma unroll
        for (int j = 0; j < 8; ++j) { w0[j] = w1[j]; w1[j] = w2[j]; w2[j] = w3[j]; w3[j] = w4[j]; }
    }
}

// Phase 2: role-split pipeline with FULLY PARALLEL repair (r12's split + r6's
// 9-wave repair). Per interval: waves 0..8 each repair ONE zone row (single
// L3-latency hop), wave 9 concurrently scans "best outside the zone" (with
// overrides for the previous zone). ONE barrier per interval; next peak is a
// 10-candidate combine. Selection exactly lexicographic (val desc, row asc,
// col asc). grid = 128, block = 640 (10 waves).
__global__ void __launch_bounds__(640) phase2_kernel(const float* __restrict__ hm_all,
                              const float* __restrict__ rowv_ws,
                              const int* __restrict__ rowc_ws,
                              int* __restrict__ out) {
    int b = blockIdx.x;
    const float* hm = hm_all + (size_t)b * HM_W * HM_H;
    int t = threadIdx.x;
    int wave = t >> 6, lane = t & 63;
    int c0 = lane * 8;

    __shared__ float rowv[512];
    __shared__ int   rowc[512];
    __shared__ float updv[2][9];
    __shared__ int   updc[2][9];
    __shared__ float obv[2];
    __shared__ int   obr[2], obc[2];

    if (t < 512) {
        if (t < PW) { rowv[t] = rowv_ws[b * 512 + t]; rowc[t] = rowc_ws[b * 512 + t]; }
        else        { rowv[t] = -__builtin_inff();    rowc[t] = 0; }
    }
    __syncthreads();

    int zrr[6], zcc[6];
    int pz0 = 0, pzn = 0;                  // previous zone range (uniform)
    int fr, fc;

    // ---- interval 0 bootstrap: full scan (LDS only), all waves redundant ----
    {
        float bv = -__builtin_inff(); int bi = 0x7fffffff;
#pragma unroll
        for (int j = 0; j < 8; ++j) {
            int idx = j * 64 + lane;
            float v = rowv[idx];
            if (v > bv) { bv = v; bi = idx; }   // ascending idx: lowest row on tie
        }
#pragma unroll
        for (int m = 1; m < 64; m <<= 1) {
            float ov = __shfl_xor(bv, m);
            int   oi = __shfl_xor(bi, m);
            if (ov > bv || (ov == bv && oi < bi)) { bv = ov; bi = oi; }
        }
        fr = bi; fc = rowc[fr];
    }
    zrr[0] = fr; zcc[0] = fc;
    if (t == 0) {
        out[b * 12 + 0] = fc + 2;   // SWAP_RC: (c+R, r+R)
        out[b * 12 + 1] = fr + 2;
    }

#pragma unroll
    for (int it = 0; it < 5; ++it) {
        int wbuf = it & 1;                 // this interval's repair buffer
        int rbuf = wbuf ^ 1;               // previous interval's repairs

        int zlo = fr - 4 < 0 ? 0 : fr - 4;
        int zhi = fr + 4 > PW - 1 ? PW - 1 : fr + 4;
        int zn  = zhi - zlo + 1;

        // ---- patch rowv/rowc with the previous zone's repairs (race-benign:
        //      the scanner reads those rows via the updv[rbuf] override) ----
        if (t < 9 && t < pzn) {
            rowv[pz0 + t] = updv[rbuf][t];
            rowc[pz0 + t] = updc[rbuf][t];
        }

        if (wave < 9) {
            // ---- repair: wave w recomputes zone row zlo+w (ONE row per wave,
            //      one parallel L3 hop; loads issue immediately) ----
            if (wave < zn) {               // wave-uniform
                int y = zlo + wave;
                float s[8];
#pragma unroll
                for (int j = 0; j < 8; ++j) s[j] = 0.f;
#pragma unroll
                for (int i = 0; i < 5; ++i) {
                    float v[8];
                    load_row8(hm, y + i, c0, v);
#pragma unroll
                    for (int k = 0; k < 6; ++k) {
                        if (k <= it) {     // compile-time under unroll
                            if ((unsigned)(y + i - zrr[k]) < 5u) {   // wave-uniform branch
#pragma unroll
                                for (int j = 0; j < 8; ++j)
                                    if ((unsigned)(c0 + j - zcc[k]) < 5u) v[j] = 0.f;
                            }
                        }
                    }
#pragma unroll
                    for (int j = 0; j < 8; ++j) s[j] += v[j];
                }
                float nv; int nc;
                row_best_shfl(s, lane, nv, nc);
                if (lane == 0) { updv[wbuf][wave] = nv; updc[wbuf][wave] = nc; }
            }
        } else {
            // ---- wave 9: best over rows OUTSIDE the current zone, overriding
            //      the previous zone's rows from updv[rbuf] ----
            float bv = -__builtin_inff(); int bi = 0x7fffffff;
#pragma unroll
            for (int j = 0; j < 8; ++j) {
                int idx = j * 64 + lane;
                float v = rowv[idx];
                unsigned u = (unsigned)(idx - pz0);
                if (u < (unsigned)pzn) v = updv[rbuf][u];
                if ((unsigned)(idx - zlo) < (unsigned)zn) v = -__builtin_inff();
                if (v > bv) { bv = v; bi = idx; }
            }
#pragma unroll
            for (int m = 1; m < 64; m <<= 1) {
                float ov = __shfl_xor(bv, m);
                int   oi = __shfl_xor(bi, m);
                if (ov > bv || (ov == bv && oi < bi)) { bv = ov; bi = oi; }
            }
            if (lane == 0) {
                int bc2 = rowc[bi];
                unsigned u = (unsigned)(bi - pz0);
                if (u < (unsigned)pzn) bc2 = updc[rbuf][u];
                obv[wbuf] = bv; obr[wbuf] = bi; obc[wbuf] = bc2;
            }
        }

        __syncthreads();   // the ONLY barrier per interval

        // ---- combine: outside-best + the zn repaired zone rows (ascending) ----
        {
            float bv = obv[wbuf]; int br = obr[wbuf]; int bc2 = obc[wbuf];
#pragma unroll
            for (int u = 0; u < 9; ++u) {
                if (u < zn) {
                    int yy = zlo + u;
                    float v = updv[wbuf][u];
                    if (v > bv || (v == bv && yy < br)) { bv = v; br = yy; bc2 = updc[wbuf][u]; }
                }
            }
            fr = br; fc = bc2;
        }
        zrr[it + 1] = fr; zcc[it + 1] = fc;   // static index under unroll
        if (t == 0) {
            out[b * 12 + (it + 1) * 2 + 0] = fc + 2;
            out[b * 12 + (it + 1) * 2 + 1] = fr + 2;
        }

        pz0 = zlo; pzn = zn;
    }
}

extern "C" void kernel_launch(void* const* d_in, const int* in_sizes, int n_in,
                              void* d_out, int out_size, void* d_ws, size_t ws_size,
                              hipStream_t stream) {
    const float* hm = (const float*)d_in[0];
    int* out = (int*)d_out;
    float* rowv_ws = (float*)d_ws;
    int*   rowc_ws = (int*)((char*)d_ws + (size_t)128 * 512 * sizeof(float));

    phase1_kernel<<<dim3(8, 128), dim3(256), 0, stream>>>(hm, rowv_ws, rowc_ws);
    phase2_kernel<<<dim3(128), dim3(640), 0, stream>>>(hm, rowv_ws, rowc_ws, out);
}